// Round 3
// baseline (469.486 us; speedup 1.0000x reference)
//
#include <hip/hip_runtime.h>
#include <math.h>

// SingleRoIExtractor: 4-level FPN RoIAlign (mmdet legacy, aligned=False)
// One block per roi. Stage per-channel patch rectangle into LDS (coalesced),
// double-buffered over the 256-channel loop; 196 threads compute 49 bins x 4
// samples from LDS with quad-shuffle reduction.
// Level mapping => scaled roi extent ~14-28px; worst-case patch (incl. odd-stride
// pad) <= ~1254 floats. LDS 2*1536*4B = 12KB -> 8 blocks/CU.

#define OUT_SZ 7
#define NCH 256
#define NBINS 49
#define PF 6          // max staged elements per thread (ceil(1536/256))
#define LDS_N 1536    // per-buffer floats; covers worst-case rows*(Wse|1)

__global__ __launch_bounds__(256)
void roi_align_fused(const float* __restrict__ f0, const float* __restrict__ f1,
                     const float* __restrict__ f2, const float* __restrict__ f3,
                     const float* __restrict__ rois,
                     float* __restrict__ out)
{
    __shared__ float lds[2][LDS_N];

    const int k = blockIdx.x;
    const int t = threadIdx.x;

    // ---- per-roi params (computed redundantly by every thread) ----
    float rb   = rois[k * 5 + 0];
    float rix1 = rois[k * 5 + 1];
    float riy1 = rois[k * 5 + 2];
    float rix2 = rois[k * 5 + 3];
    float riy2 = rois[k * 5 + 4];

    float scale = sqrtf((rix2 - rix1 + 1.0f) * (riy2 - riy1 + 1.0f));
    int lvl = (int)floorf(log2f(scale * (1.0f / 56.0f) + 1e-6f));
    lvl = lvl < 0 ? 0 : (lvl > 3 ? 3 : lvl);

    float ss = 1.0f / (float)(4 << lvl);
    float x1 = rix1 * ss, y1 = riy1 * ss;
    float rw = fmaxf(rix2 * ss - x1, 1.0f);
    float rh = fmaxf(riy2 * ss - y1, 1.0f);
    float bw = rw * (1.0f / OUT_SZ);
    float bh = rh * (1.0f / OUT_SZ);
    const int H = 800  >> (2 + lvl);
    const int W = 1216 >> (2 + lvl);
    const float fH = (float)H, fW = (float)W;

    const float* fb = (lvl == 0) ? f0 : (lvl == 1) ? f1 : (lvl == 2) ? f2 : f3;
    const int HW = H * W;
    const float* base = fb + (size_t)((int)rb * NCH) * (size_t)HW;

    // ---- patch bounds from first/last samples (positions monotonic in j) ----
    float xf0 = fminf(fmaxf(x1 + 0.25f * bw, 0.0f), fW - 1.0f);
    float xfl = fminf(fmaxf(x1 + 6.75f * bw, 0.0f), fW - 1.0f);
    int xa = (int)floorf(xf0);
    int xb = min((int)floorf(xfl) + 1, W - 1);
    float yf0 = fminf(fmaxf(y1 + 0.25f * bh, 0.0f), fH - 1.0f);
    float yfl = fminf(fmaxf(y1 + 6.75f * bh, 0.0f), fH - 1.0f);
    int ya = (int)floorf(yf0);
    int yb = min((int)floorf(yfl) + 1, H - 1);

    int Wse    = xb - xa + 1;
    int Rows   = yb - ya + 1;
    int stride = Wse | 1;          // odd LDS stride to break bank patterns
    int S      = Rows * Wse;       // staged element count

    // ---- per-thread staging offsets (same every channel) ----
    int goff[PF], loff[PF];
    bool gv[PF];
#pragma unroll
    for (int i = 0; i < PF; ++i) {
        int idx = t + 256 * i;
        gv[i] = idx < S;
        int idx2 = gv[i] ? idx : 0;
        int r   = idx2 / Wse;
        int col = idx2 - r * Wse;
        goff[i] = (ya + r) * W + xa + col;
        loff[i] = r * stride + col;
    }

    // ---- per-thread sample params (threads 0..195: bin = t>>2, sample = t&3) ----
    int bin = t >> 2;
    int s   = t & 3;
    int sy  = s >> 1;
    int sx  = s & 1;
    int oy  = bin / OUT_SZ;
    int ox  = bin - oy * OUT_SZ;

    float xs  = x1 + ((float)(2 * ox + sx) + 0.5f) * 0.5f * bw;
    float ysv = y1 + ((float)(2 * oy + sy) + 0.5f) * 0.5f * bh;
    bool vx = (xs  >= -1.0f) && (xs  <= fW);
    bool vy = (ysv >= -1.0f) && (ysv <= fH);
    bool vall = vx && vy;

    float xc = fminf(fmaxf(xs, 0.0f), fW - 1.0f);
    float yc = fminf(fmaxf(ysv, 0.0f), fH - 1.0f);
    float xflr = floorf(xc), yflr = floorf(yc);
    int x0 = (int)xflr, y0 = (int)yflr;
    float lx = xc - xflr, ly = yc - yflr;
    int xhi = min(x0 + 1, W - 1);
    int yhi = min(y0 + 1, H - 1);

    int lcx0 = x0  - xa;            // LDS col offsets
    int lcx1 = xhi - xa;
    int lro0 = (y0  - ya) * stride; // LDS row offsets
    int lro1 = (yhi - ya) * stride;
    float w00 = (1.0f - ly) * (1.0f - lx);
    float w01 = (1.0f - ly) * lx;
    float w10 = ly * (1.0f - lx);
    float w11 = ly * lx;

    // ---- prologue: stage channel 0 into buf 0 ----
    float pv[PF];
#pragma unroll
    for (int i = 0; i < PF; ++i) pv[i] = gv[i] ? base[goff[i]] : 0.0f;
#pragma unroll
    for (int i = 0; i < PF; ++i) if (gv[i]) lds[0][loff[i]] = pv[i];
    __syncthreads();

    float* outk = out + (size_t)k * (NCH * NBINS);
    int p = 0;

    for (int c = 0; c < NCH; ++c) {
        // prefetch next channel's patch into registers (no LDS write yet)
        if (c + 1 < NCH) {
            const float* pn = base + (size_t)(c + 1) * HW;
#pragma unroll
            for (int i = 0; i < PF; ++i) pv[i] = gv[i] ? pn[goff[i]] : 0.0f;
        }

        // compute current channel from lds[p]
        if (t < 196) {
            const float* L = lds[p];
            float v00 = L[lro0 + lcx0];
            float v01 = L[lro0 + lcx1];
            float v10 = L[lro1 + lcx0];
            float v11 = L[lro1 + lcx1];
            float val = vall ? (v00 * w00 + v01 * w01 + v10 * w10 + v11 * w11)
                             : 0.0f;
            val += __shfl_xor(val, 1, 64);
            val += __shfl_xor(val, 2, 64);
            if (s == 0) outk[c * NBINS + bin] = val * 0.25f;
        }
        __syncthreads();

        // commit prefetched data into the other buffer
        if (c + 1 < NCH) {
#pragma unroll
            for (int i = 0; i < PF; ++i) if (gv[i]) lds[p ^ 1][loff[i]] = pv[i];
        }
        __syncthreads();
        p ^= 1;
    }
}

extern "C" void kernel_launch(void* const* d_in, const int* in_sizes, int n_in,
                              void* d_out, int out_size, void* d_ws, size_t ws_size,
                              hipStream_t stream)
{
    const float* f0   = (const float*)d_in[0];
    const float* f1   = (const float*)d_in[1];
    const float* f2   = (const float*)d_in[2];
    const float* f3   = (const float*)d_in[3];
    const float* rois = (const float*)d_in[4];
    float* out = (float*)d_out;

    int K = in_sizes[4] / 5;
    if (K <= 0) return;

    roi_align_fused<<<K, 256, 0, stream>>>(f0, f1, f2, f3, rois, out);
}

// Round 4
// 334.164 us; speedup vs baseline: 1.4050x; 1.4050x over previous
//
#include <hip/hip_runtime.h>
#include <math.h>

// SingleRoIExtractor: 4-level FPN RoIAlign (mmdet legacy, aligned=False)
// Block = (roi, 64-channel group) -> 4096 blocks (8/CU resident, 18KB LDS each).
// Ring-3 LDS buffers, ONE barrier per channel; depth-2 global prefetch in regs.
// 196 threads compute 49 bins x 4 samples from LDS, quad-shuffle reduce.

#define OUT_SZ 7
#define NCH 256
#define NBINS 49
#define CGC 64        // channels per block
#define NGROUPS 4     // NCH / CGC
#define PF 6          // staged elements per thread (ceil(LDS_N/256))
#define LDS_N 1536    // per-channel buffer floats (worst-case patch ~1000)

__global__ __launch_bounds__(256)
void roi_align_fused(const float* __restrict__ f0, const float* __restrict__ f1,
                     const float* __restrict__ f2, const float* __restrict__ f3,
                     const float* __restrict__ rois,
                     float* __restrict__ out)
{
    __shared__ float lds[3][LDS_N];

    const int k = blockIdx.x;
    const int g = blockIdx.y;
    const int t = threadIdx.x;

    // ---- per-roi params ----
    float rb   = rois[k * 5 + 0];
    float rix1 = rois[k * 5 + 1];
    float riy1 = rois[k * 5 + 2];
    float rix2 = rois[k * 5 + 3];
    float riy2 = rois[k * 5 + 4];

    float scale = sqrtf((rix2 - rix1 + 1.0f) * (riy2 - riy1 + 1.0f));
    int lvl = (int)floorf(log2f(scale * (1.0f / 56.0f) + 1e-6f));
    lvl = lvl < 0 ? 0 : (lvl > 3 ? 3 : lvl);

    float ss = 1.0f / (float)(4 << lvl);
    float x1 = rix1 * ss, y1 = riy1 * ss;
    float rw = fmaxf(rix2 * ss - x1, 1.0f);
    float rh = fmaxf(riy2 * ss - y1, 1.0f);
    float bw = rw * (1.0f / OUT_SZ);
    float bh = rh * (1.0f / OUT_SZ);
    const int H = 800  >> (2 + lvl);
    const int W = 1216 >> (2 + lvl);
    const float fH = (float)H, fW = (float)W;

    const float* fb = (lvl == 0) ? f0 : (lvl == 1) ? f1 : (lvl == 2) ? f2 : f3;
    const int HW = H * W;
    const float* cbase = fb + ((size_t)((int)rb * NCH) + (size_t)(g * CGC)) * (size_t)HW;

    // ---- patch bounds from first/last samples (monotonic) ----
    float xf0 = fminf(fmaxf(x1 + 0.25f * bw, 0.0f), fW - 1.0f);
    float xfl = fminf(fmaxf(x1 + 6.75f * bw, 0.0f), fW - 1.0f);
    int xa = (int)floorf(xf0);
    int xb = min((int)floorf(xfl) + 1, W - 1);
    float yf0 = fminf(fmaxf(y1 + 0.25f * bh, 0.0f), fH - 1.0f);
    float yfl = fminf(fmaxf(y1 + 6.75f * bh, 0.0f), fH - 1.0f);
    int ya = (int)floorf(yf0);
    int yb = min((int)floorf(yfl) + 1, H - 1);

    int Wse    = xb - xa + 1;
    int Rows   = yb - ya + 1;
    int stride = Wse | 1;          // odd LDS stride
    int S      = Rows * Wse;

    // ---- staging offsets (same for every channel) ----
    int goff[PF], loff[PF];
    bool gv[PF];
#pragma unroll
    for (int i = 0; i < PF; ++i) {
        int idx = t + 256 * i;
        gv[i] = idx < S;
        int idx2 = gv[i] ? idx : 0;
        int r   = idx2 / Wse;
        int col = idx2 - r * Wse;
        goff[i] = (ya + r) * W + xa + col;
        loff[i] = r * stride + col;
    }

    // ---- sample params (threads 0..195: bin = t>>2, sample = t&3) ----
    int bin = t >> 2;
    int s   = t & 3;
    int sy  = s >> 1;
    int sx  = s & 1;
    int oy  = bin / OUT_SZ;
    int ox  = bin - oy * OUT_SZ;

    float xs  = x1 + ((float)(2 * ox + sx) + 0.5f) * 0.5f * bw;
    float ysv = y1 + ((float)(2 * oy + sy) + 0.5f) * 0.5f * bh;
    bool vall = (xs >= -1.0f) && (xs <= fW) && (ysv >= -1.0f) && (ysv <= fH);

    float xc = fminf(fmaxf(xs, 0.0f), fW - 1.0f);
    float yc = fminf(fmaxf(ysv, 0.0f), fH - 1.0f);
    float xflr = floorf(xc), yflr = floorf(yc);
    int x0 = (int)xflr, y0 = (int)yflr;
    float lx = xc - xflr, ly = yc - yflr;
    int xhi = min(x0 + 1, W - 1);
    int yhi = min(y0 + 1, H - 1);

    int lcx0 = x0  - xa;
    int lcx1 = xhi - xa;
    int lro0 = (y0  - ya) * stride;
    int lro1 = (yhi - ya) * stride;
    float w00 = (1.0f - ly) * (1.0f - lx);
    float w01 = (1.0f - ly) * lx;
    float w10 = ly * (1.0f - lx);
    float w11 = ly * lx;

    // ---- prologue: ch0 -> buf0; ch1 -> pvA (odd set); ch2 -> pvB (even set) ----
    float pvA[PF], pvB[PF], t0[PF];
#pragma unroll
    for (int i = 0; i < PF; ++i) t0[i] = gv[i] ? cbase[goff[i]] : 0.0f;
#pragma unroll
    for (int i = 0; i < PF; ++i) if (gv[i]) lds[0][loff[i]] = t0[i];
    {
        const float* p1 = cbase + (size_t)HW;
        const float* p2 = cbase + 2 * (size_t)HW;
#pragma unroll
        for (int i = 0; i < PF; ++i) pvA[i] = gv[i] ? p1[goff[i]] : 0.0f;
#pragma unroll
        for (int i = 0; i < PF; ++i) pvB[i] = gv[i] ? p2[goff[i]] : 0.0f;
    }
    __syncthreads();

    float* outk = out + (size_t)k * (NCH * NBINS) + (size_t)(g * CGC) * NBINS;

    for (int c = 0; c < CGC; ++c) {
        // commit ch c+1 (loaded 2 iters ago) into buf (c+1)%3
        if (c + 1 < CGC) {
            float* dst = lds[(c + 1) % 3];
            if ((c + 1) & 1) {
#pragma unroll
                for (int i = 0; i < PF; ++i) if (gv[i]) dst[loff[i]] = pvA[i];
            } else {
#pragma unroll
                for (int i = 0; i < PF; ++i) if (gv[i]) dst[loff[i]] = pvB[i];
            }
        }
        // issue loads for ch c+3 into the register set just freed
        if (c + 3 < CGC) {
            const float* pn = cbase + (size_t)(c + 3) * HW;
            if ((c + 3) & 1) {
#pragma unroll
                for (int i = 0; i < PF; ++i) pvA[i] = gv[i] ? pn[goff[i]] : 0.0f;
            } else {
#pragma unroll
                for (int i = 0; i < PF; ++i) pvB[i] = gv[i] ? pn[goff[i]] : 0.0f;
            }
        }
        // compute ch c from buf c%3
        if (t < 196) {
            const float* L = lds[c % 3];
            float v00 = L[lro0 + lcx0];
            float v01 = L[lro0 + lcx1];
            float v10 = L[lro1 + lcx0];
            float v11 = L[lro1 + lcx1];
            float val = vall ? (v00 * w00 + v01 * w01 + v10 * w10 + v11 * w11)
                             : 0.0f;
            val += __shfl_xor(val, 1, 64);
            val += __shfl_xor(val, 2, 64);
            if (s == 0) outk[c * NBINS + bin] = val * 0.25f;
        }
        __syncthreads();
    }
}

extern "C" void kernel_launch(void* const* d_in, const int* in_sizes, int n_in,
                              void* d_out, int out_size, void* d_ws, size_t ws_size,
                              hipStream_t stream)
{
    const float* f0   = (const float*)d_in[0];
    const float* f1   = (const float*)d_in[1];
    const float* f2   = (const float*)d_in[2];
    const float* f3   = (const float*)d_in[3];
    const float* rois = (const float*)d_in[4];
    float* out = (float*)d_out;

    int K = in_sizes[4] / 5;
    if (K <= 0) return;

    roi_align_fused<<<dim3(K, NGROUPS), 256, 0, stream>>>(f0, f1, f2, f3, rois, out);
}

// Round 6
// 314.423 us; speedup vs baseline: 1.4932x; 1.0628x over previous
//
#include <hip/hip_runtime.h>
#include <math.h>

// SingleRoIExtractor: 4-level FPN RoIAlign (mmdet legacy, aligned=False)
// Block = (roi, 64-channel group). Ring-2 LDS buffers (one barrier/channel is
// sufficient: WAR and RAW on each buffer are separated by exactly one barrier),
// depth-2 global prefetch in regs. Staging via 16B-aligned float4 chunks
// (levels 0-2; level 3 W=38 -> 8B-aligned float2 chunks).
// LDS row slot = cpr*V+1 (odd, holds whole chunks -> no cross-row clobber).
// Worst patch: 142 rows x stride 13 = 1846 floats -> LDS_N=1920.
// 2*1920*4B = 15KB/block -> 8 blocks/CU.

#define OUT_SZ 7
#define NCH 256
#define NBINS 49
#define CGC 64
#define NGROUPS 4
#define LDS_N 1920

template<int VSH>
__device__ __forceinline__ void roi_group(
    const float* __restrict__ cbase, int CLrel, int HW, int H, int W,
    float x1, float y1, float bw, float bh,
    int t, float* __restrict__ outk, float (*lds)[LDS_N])
{
    const int V = 1 << VSH;
    const float fH = (float)H, fW = (float)W;

    // ---- patch bounds from first/last samples (monotonic in sample idx) ----
    float xf0 = fminf(fmaxf(x1 + 0.25f * bw, 0.0f), fW - 1.0f);
    float xfl = fminf(fmaxf(x1 + 6.75f * bw, 0.0f), fW - 1.0f);
    int xa = (int)floorf(xf0);
    int xb = min((int)floorf(xfl) + 1, W - 1);
    float yf0 = fminf(fmaxf(y1 + 0.25f * bh, 0.0f), fH - 1.0f);
    float yfl = fminf(fmaxf(y1 + 6.75f * bh, 0.0f), fH - 1.0f);
    int ya = (int)floorf(yf0);
    int yb = min((int)floorf(yfl) + 1, H - 1);

    int axa    = xa & ~(V - 1);            // aligned col base
    int cpr    = ((xb - axa) >> VSH) + 1;  // chunks per row
    int stride = (cpr << VSH) + 1;         // LDS row slot: holds cpr full chunks, odd
    int Rows   = yb - ya + 1;
    int C      = Rows * cpr;               // total chunks (<= ~430)

    // ---- per-thread chunk offsets (chunks q = t, t+256) ----
    int goff[2], loff[2];
    bool act[2];
#pragma unroll
    for (int i = 0; i < 2; ++i) {
        int q = t + 256 * i;
        act[i] = q < C;
        int qq = act[i] ? q : 0;
        int r  = qq / cpr;
        int j  = qq - r * cpr;
        int rowbase = (ya + r) * W;
        int rel  = rowbase + axa + (j << VSH);
        int relc = min(rel, CLrel);        // tensor-end clamp (keeps alignment;
                                           // shifted chunk still covers needed cols)
        goff[i] = relc;
        loff[i] = r * stride + (relc - rowbase - axa);
    }

    // ---- sample params (threads 0..195: bin = t>>2, sample = t&3) ----
    int bin = t >> 2;
    int s   = t & 3;
    int oy  = bin / OUT_SZ;
    int ox  = bin - oy * OUT_SZ;

    float xs  = x1 + ((float)(2 * ox + (s & 1)) + 0.5f) * 0.5f * bw;
    float ysv = y1 + ((float)(2 * oy + (s >> 1)) + 0.5f) * 0.5f * bh;
    bool vall = (xs >= -1.0f) && (xs <= fW) && (ysv >= -1.0f) && (ysv <= fH);

    float xc = fminf(fmaxf(xs, 0.0f), fW - 1.0f);
    float yc = fminf(fmaxf(ysv, 0.0f), fH - 1.0f);
    float xflr = floorf(xc), yflr = floorf(yc);
    int x0 = (int)xflr, y0 = (int)yflr;
    float lx = xc - xflr, ly = yc - yflr;
    int xhi = min(x0 + 1, W - 1);
    int yhi = min(y0 + 1, H - 1);

    int lcx0 = x0  - axa;
    int lcx1 = xhi - axa;
    int lro0 = (y0  - ya) * stride;
    int lro1 = (yhi - ya) * stride;
    float w00 = (1.0f - ly) * (1.0f - lx);
    float w01 = (1.0f - ly) * lx;
    float w10 = ly * (1.0f - lx);
    float w11 = ly * lx;

    auto ldchunk = [&](const float* p, int i) -> float4 {
        float4 v = make_float4(0.f, 0.f, 0.f, 0.f);
        if (act[i]) {
            if (VSH == 2) {
                v = *(const float4*)(p + goff[i]);
            } else {
                float2 h2 = *(const float2*)(p + goff[i]);
                v.x = h2.x; v.y = h2.y;
            }
        }
        return v;
    };
    auto stchunk = [&](float* dst, int i, float4 v) {
        if (act[i]) {
            float* d = dst + loff[i];
            d[0] = v.x; d[1] = v.y;
            if (VSH == 2) { d[2] = v.z; d[3] = v.w; }
        }
    };

    // ---- prologue: ch0 -> buf0; ch1 -> pvA; ch2 -> pvB ----
    float4 pvA[2], pvB[2], t0[2];
    t0[0]  = ldchunk(cbase, 0);
    pvA[0] = ldchunk(cbase + (size_t)HW, 0);
    pvB[0] = ldchunk(cbase + 2 * (size_t)HW, 0);
    if (C > 256) {
        t0[1]  = ldchunk(cbase, 1);
        pvA[1] = ldchunk(cbase + (size_t)HW, 1);
        pvB[1] = ldchunk(cbase + 2 * (size_t)HW, 1);
    }
    stchunk(lds[0], 0, t0[0]);
    if (C > 256) stchunk(lds[0], 1, t0[1]);
    __syncthreads();

    for (int c = 0; c < CGC; ++c) {
        // commit ch c+1 (loads issued 2 iters ago) into buf (c+1)&1
        if (c + 1 < CGC) {
            float* dst = lds[(c + 1) & 1];
            float4* src = ((c + 1) & 1) ? pvA : pvB;
            stchunk(dst, 0, src[0]);
            if (C > 256) stchunk(dst, 1, src[1]);
        }
        // issue loads for ch c+3 into the register set just freed
        if (c + 3 < CGC) {
            const float* pn = cbase + (size_t)(c + 3) * HW;
            float4* dr = ((c + 3) & 1) ? pvA : pvB;
            dr[0] = ldchunk(pn, 0);
            if (C > 256) dr[1] = ldchunk(pn, 1);
        }
        // compute ch c from buf c&1
        if (t < 196) {
            const float* L = lds[c & 1];
            float v00 = L[lro0 + lcx0];
            float v01 = L[lro0 + lcx1];
            float v10 = L[lro1 + lcx0];
            float v11 = L[lro1 + lcx1];
            float val = vall ? (v00 * w00 + v01 * w01 + v10 * w10 + v11 * w11)
                             : 0.0f;
            val += __shfl_xor(val, 1, 64);
            val += __shfl_xor(val, 2, 64);
            if (s == 0) outk[c * NBINS + bin] = val * 0.25f;
        }
        __syncthreads();
    }
}

__global__ __launch_bounds__(256)
void roi_align_fused(const float* __restrict__ f0, const float* __restrict__ f1,
                     const float* __restrict__ f2, const float* __restrict__ f3,
                     const float* __restrict__ rois,
                     float* __restrict__ out)
{
    __shared__ float lds[2][LDS_N];

    const int k = blockIdx.x;
    const int g = blockIdx.y;
    const int t = threadIdx.x;

    float rb   = rois[k * 5 + 0];
    float rix1 = rois[k * 5 + 1];
    float riy1 = rois[k * 5 + 2];
    float rix2 = rois[k * 5 + 3];
    float riy2 = rois[k * 5 + 4];

    float scale = sqrtf((rix2 - rix1 + 1.0f) * (riy2 - riy1 + 1.0f));
    int lvl = (int)floorf(log2f(scale * (1.0f / 56.0f) + 1e-6f));
    lvl = lvl < 0 ? 0 : (lvl > 3 ? 3 : lvl);

    float ss = 1.0f / (float)(4 << lvl);
    float x1 = rix1 * ss, y1 = riy1 * ss;
    float rw = fmaxf(rix2 * ss - x1, 1.0f);
    float rh = fmaxf(riy2 * ss - y1, 1.0f);
    float bw = rw * (1.0f / OUT_SZ);
    float bh = rh * (1.0f / OUT_SZ);
    const int H = 800  >> (2 + lvl);
    const int W = 1216 >> (2 + lvl);

    const float* fb = (lvl == 0) ? f0 : (lvl == 1) ? f1 : (lvl == 2) ? f2 : f3;
    const int HW  = H * W;
    const int TOT = 2 * NCH * HW;
    const int base_off = ((int)rb * NCH + g * CGC) * HW;
    const float* cbase = fb + base_off;
    float* outk = out + ((size_t)k * NCH + (size_t)(g * CGC)) * NBINS;

    if (W & 3) {   // level 3: only 8B global alignment guaranteed
        int CLrel = TOT - base_off - (CGC - 1) * HW - 2;
        roi_group<1>(cbase, CLrel, HW, H, W, x1, y1, bw, bh, t, outk, lds);
    } else {       // levels 0-2: 16B-aligned float4 staging
        int CLrel = TOT - base_off - (CGC - 1) * HW - 4;
        roi_group<2>(cbase, CLrel, HW, H, W, x1, y1, bw, bh, t, outk, lds);
    }
}

extern "C" void kernel_launch(void* const* d_in, const int* in_sizes, int n_in,
                              void* d_out, int out_size, void* d_ws, size_t ws_size,
                              hipStream_t stream)
{
    const float* f0   = (const float*)d_in[0];
    const float* f1   = (const float*)d_in[1];
    const float* f2   = (const float*)d_in[2];
    const float* f3   = (const float*)d_in[3];
    const float* rois = (const float*)d_in[4];
    float* out = (float*)d_out;

    int K = in_sizes[4] / 5;
    if (K <= 0) return;

    roi_align_fused<<<dim3(K, NGROUPS), 256, 0, stream>>>(f0, f1, f2, f3, rois, out);
}

// Round 7
// 310.284 us; speedup vs baseline: 1.5131x; 1.0133x over previous
//
#include <hip/hip_runtime.h>
#include <math.h>

// SingleRoIExtractor: 4-level FPN RoIAlign (mmdet legacy, aligned=False)
// Block = (roi, 64-channel group). Ring-2 LDS buffers, one barrier/channel,
// depth-2 global prefetch. Staging: 16B-aligned float4 global loads ->
// ds_write_b128 (levels 0-2; level 3 W=38 -> float2/b64). LDS row slot =
// cpr*V floats (bump +V if multiple of 32 to avoid row-aligned banks).
// x-interp reads L[p],L[p+1] unconditionally (merge to ds_read2_b32);
// overrun hits next-row data (weight 0) or zeroed pad/sentinel.
// Worst patch (h<=600 => rows<=141, stride 12) = 1704 floats -> LDS_N=1920.
// 2*1920*4B = 15 KB/block -> 8 blocks/CU.

#define OUT_SZ 7
#define NCH 256
#define NBINS 49
#define CGC 64
#define NGROUPS 4
#define LDS_N 1920

template<int VSH>
__device__ __forceinline__ void roi_group(
    const float* __restrict__ cbase, int CLrel, int HW, int H, int W,
    float x1, float y1, float bw, float bh,
    int t, float* __restrict__ outk, float (*lds)[LDS_N])
{
    const int V = 1 << VSH;
    const float fH = (float)H, fW = (float)W;

    // ---- patch bounds from first/last samples (monotonic in sample idx) ----
    float xf0 = fminf(fmaxf(x1 + 0.25f * bw, 0.0f), fW - 1.0f);
    float xfl = fminf(fmaxf(x1 + 6.75f * bw, 0.0f), fW - 1.0f);
    int xa = (int)floorf(xf0);
    int xb = min((int)floorf(xfl) + 1, W - 1);
    float yf0 = fminf(fmaxf(y1 + 0.25f * bh, 0.0f), fH - 1.0f);
    float yfl = fminf(fmaxf(y1 + 6.75f * bh, 0.0f), fH - 1.0f);
    int ya = (int)floorf(yf0);
    int yb = min((int)floorf(yfl) + 1, H - 1);

    int axa    = xa & ~(V - 1);            // aligned col base
    int cpr    = ((xb - axa) >> VSH) + 1;  // chunks per row
    int rowlen = cpr << VSH;
    int stride = rowlen + (((rowlen & 31) == 0) ? V : 0);  // keep V-aligned, break 32-multiples
    int Rows   = yb - ya + 1;
    int C      = Rows * cpr;               // total chunks

    // ---- zero sentinel + pad (targets of weight-0 overrun reads) ----
    {
        int sent = Rows * stride;          // <= ~1704 < LDS_N
        if (t == 0) { lds[0][sent] = 0.0f; lds[1][sent] = 0.0f; }
        int padw = stride - rowlen;
        if (padw) {
            int np = Rows * padw;
            for (int z = t; z < np; z += 256) {
                int zr = z / padw, zc = z - zr * padw;
                int idx = zr * stride + rowlen + zc;
                lds[0][idx] = 0.0f;
                lds[1][idx] = 0.0f;
            }
        }
    }

    // ---- staging chunk assignment (rotated: lanes >=196 take chunks first) ----
    int q0 = (t + 60) & 255;
    int goff[2], loff[2];
    bool act[2];
#pragma unroll
    for (int i = 0; i < 2; ++i) {
        int q = q0 + 256 * i;
        act[i] = q < C;
        int qq = act[i] ? q : 0;
        int r  = qq / cpr;
        int j  = qq - r * cpr;
        int rowbase = (ya + r) * W;
        int rel  = rowbase + axa + (j << VSH);
        int relc = min(rel, CLrel);        // tensor-end clamp, V-aligned
        goff[i] = relc;
        loff[i] = r * stride + (relc - rowbase - axa);
    }

    // ---- sample params (threads 0..195: bin = t>>2, sample = t&3) ----
    int bin = t >> 2;
    int s   = t & 3;
    int oy  = bin / OUT_SZ;
    int ox  = bin - oy * OUT_SZ;

    float xs  = x1 + ((float)(2 * ox + (s & 1)) + 0.5f) * 0.5f * bw;
    float ysv = y1 + ((float)(2 * oy + (s >> 1)) + 0.5f) * 0.5f * bh;
    bool vall = (xs >= -1.0f) && (xs <= fW) && (ysv >= -1.0f) && (ysv <= fH);

    float xc = fminf(fmaxf(xs, 0.0f), fW - 1.0f);
    float yc = fminf(fmaxf(ysv, 0.0f), fH - 1.0f);
    float xflr = floorf(xc), yflr = floorf(yc);
    int x0 = (int)xflr, y0 = (int)yflr;
    float lx = xc - xflr, ly = yc - yflr;

    int p0 = (y0 - ya) * stride + (x0 - axa);
    int ry = min(y0 + 1 - ya, Rows - 1);   // y clamp (x handled by overrun+w=0)
    int p1 = ry * stride + (x0 - axa);

    float w00 = (1.0f - ly) * (1.0f - lx);
    float w01 = (1.0f - ly) * lx;
    float w10 = ly * (1.0f - lx);
    float w11 = ly * lx;

    auto ldchunk = [&](const float* p, int i) -> float4 {
        if (!act[i]) return make_float4(0.f, 0.f, 0.f, 0.f);
        if (VSH == 2) return *(const float4*)(p + goff[i]);
        float2 h2 = *(const float2*)(p + goff[i]);
        return make_float4(h2.x, h2.y, 0.f, 0.f);
    };
    auto stchunk = [&](float* dst, int i, float4 v) {
        if (act[i]) {
            if (VSH == 2) *(float4*)(dst + loff[i]) = v;
            else          *(float2*)(dst + loff[i]) = make_float2(v.x, v.y);
        }
    };

    // ---- prologue: ch0 -> buf0; ch1 -> pvA; ch2 -> pvB ----
    float4 pvA[2], pvB[2], t0[2];
    t0[0]  = ldchunk(cbase, 0);
    pvA[0] = ldchunk(cbase + (size_t)HW, 0);
    pvB[0] = ldchunk(cbase + 2 * (size_t)HW, 0);
    if (C > 256) {
        t0[1]  = ldchunk(cbase, 1);
        pvA[1] = ldchunk(cbase + (size_t)HW, 1);
        pvB[1] = ldchunk(cbase + 2 * (size_t)HW, 1);
    }
    stchunk(lds[0], 0, t0[0]);
    if (C > 256) stchunk(lds[0], 1, t0[1]);
    __syncthreads();

    for (int c = 0; c < CGC; ++c) {
        // commit ch c+1 (loads issued 2 iters ago) into buf (c+1)&1
        if (c + 1 < CGC) {
            float* dst = lds[(c + 1) & 1];
            float4* src = ((c + 1) & 1) ? pvA : pvB;
            stchunk(dst, 0, src[0]);
            if (C > 256) stchunk(dst, 1, src[1]);
        }
        // issue loads for ch c+3 into the register set just freed
        if (c + 3 < CGC) {
            const float* pn = cbase + (size_t)(c + 3) * HW;
            float4* dr = ((c + 3) & 1) ? pvA : pvB;
            dr[0] = ldchunk(pn, 0);
            if (C > 256) dr[1] = ldchunk(pn, 1);
        }
        // compute ch c from buf c&1
        if (t < 196) {
            const float* L = lds[c & 1];
            float v00 = L[p0];
            float v01 = L[p0 + 1];
            float v10 = L[p1];
            float v11 = L[p1 + 1];
            float val = vall ? (v00 * w00 + v01 * w01 + v10 * w10 + v11 * w11)
                             : 0.0f;
            val += __shfl_xor(val, 1, 64);
            val += __shfl_xor(val, 2, 64);
            if (s == 0) outk[c * NBINS + bin] = val * 0.25f;
        }
        __syncthreads();
    }
}

__global__ __launch_bounds__(256)
void roi_align_fused(const float* __restrict__ f0, const float* __restrict__ f1,
                     const float* __restrict__ f2, const float* __restrict__ f3,
                     const float* __restrict__ rois,
                     float* __restrict__ out)
{
    __shared__ __align__(16) float lds[2][LDS_N];   // LDS_N*4 % 16 == 0 -> both bufs 16B-aligned

    const int k = blockIdx.x;
    const int g = blockIdx.y;
    const int t = threadIdx.x;

    float rb   = rois[k * 5 + 0];
    float rix1 = rois[k * 5 + 1];
    float riy1 = rois[k * 5 + 2];
    float rix2 = rois[k * 5 + 3];
    float riy2 = rois[k * 5 + 4];

    float scale = sqrtf((rix2 - rix1 + 1.0f) * (riy2 - riy1 + 1.0f));
    int lvl = (int)floorf(log2f(scale * (1.0f / 56.0f) + 1e-6f));
    lvl = lvl < 0 ? 0 : (lvl > 3 ? 3 : lvl);

    float ss = 1.0f / (float)(4 << lvl);
    float x1 = rix1 * ss, y1 = riy1 * ss;
    float rw = fmaxf(rix2 * ss - x1, 1.0f);
    float rh = fmaxf(riy2 * ss - y1, 1.0f);
    float bw = rw * (1.0f / OUT_SZ);
    float bh = rh * (1.0f / OUT_SZ);
    const int H = 800  >> (2 + lvl);
    const int W = 1216 >> (2 + lvl);

    const float* fb = (lvl == 0) ? f0 : (lvl == 1) ? f1 : (lvl == 2) ? f2 : f3;
    const int HW  = H * W;
    const int TOT = 2 * NCH * HW;
    const int base_off = ((int)rb * NCH + g * CGC) * HW;
    const float* cbase = fb + base_off;
    float* outk = out + ((size_t)k * NCH + (size_t)(g * CGC)) * NBINS;

    if (W & 3) {   // level 3 (W=38, HW=950): only 8B alignment -> float2 chunks
        int CLrel = TOT - base_off - (CGC - 1) * HW - 2;
        roi_group<1>(cbase, CLrel, HW, H, W, x1, y1, bw, bh, t, outk, lds);
    } else {       // levels 0-2: 16B-aligned float4 chunks
        int CLrel = TOT - base_off - (CGC - 1) * HW - 4;
        roi_group<2>(cbase, CLrel, HW, H, W, x1, y1, bw, bh, t, outk, lds);
    }
}

extern "C" void kernel_launch(void* const* d_in, const int* in_sizes, int n_in,
                              void* d_out, int out_size, void* d_ws, size_t ws_size,
                              hipStream_t stream)
{
    const float* f0   = (const float*)d_in[0];
    const float* f1   = (const float*)d_in[1];
    const float* f2   = (const float*)d_in[2];
    const float* f3   = (const float*)d_in[3];
    const float* rois = (const float*)d_in[4];
    float* out = (float*)d_out;

    int K = in_sizes[4] / 5;
    if (K <= 0) return;

    roi_align_fused<<<dim3(K, NGROUPS), 256, 0, stream>>>(f0, f1, f2, f3, rois, out);
}